// Round 7
// baseline (49.450 us; speedup 1.0000x reference)
//
#include <hip/hip_runtime.h>
#include <stdint.h>
#include <math.h>

// Problem geometry (fixed by reference)
#define HWPIX 65536         // 256*256
#define NCH   18
#define NHYP  1024
#define NK    9
#define NBK   72            // B*K = 8*9
#define INV_LOG2 1.4426950408889634f
#define TINYF 1.1754943508222875e-38f

// pixel part: 2048 blocks = [side(2)][b(8)][half(2)][blk64(64)], 256 thr
// hyp part:   144 blocks appended (bid 2048..2191)
#define NPIXB 2048
#define NVB_SIDE 1024       // vote partials per side
#define NSB_SIDE 512        // seg/cnt partials per side (half==0 blocks)

// ws layout (floats)
#define OFS_VOTE 64                          // [2][NVB_SIDE]
#define OFS_CNT  (OFS_VOTE + 2 * NVB_SIDE)   // [2][NSB_SIDE]
#define OFS_SEG  (OFS_CNT  + 2 * NSB_SIDE)   // [2][NSB_SIDE]
#define OFS_KP   (OFS_SEG  + 2 * NSB_SIDE)   // [2][NBK]
#define OFS_ENT  (OFS_KP   + 2 * NBK)        // [2][NBK]
#define OFS_Y    (OFS_ENT  + 2 * NBK)        // [2][NBK]

// native clang vector types (accepted by __builtin_nontemporal_load / asm "v")
typedef float fx4 __attribute__((ext_vector_type(4)));
typedef int   ix4 __attribute__((ext_vector_type(4)));

// inline-asm non-temporal 16B load — compiler cannot re-serialize these
#define GL4NT(dst, ptr) \
  asm volatile("global_load_dwordx4 %0, %1, off nt" : "=v"(dst) : "v"(ptr) : "memory")

// ---- Threefry-2x32, 20 rounds (JAX-compatible) ----
__host__ __device__ inline void tf2x32(uint32_t k0, uint32_t k1,
                                       uint32_t x0, uint32_t x1,
                                       uint32_t& o0, uint32_t& o1) {
  uint32_t ks2 = k0 ^ k1 ^ 0x1BD11BDAu;
  x0 += k0; x1 += k1;
#define TFR(r) { x0 += x1; x1 = (x1 << (r)) | (x1 >> (32 - (r))); x1 ^= x0; }
  TFR(13) TFR(15) TFR(26) TFR(6)   x0 += k1;  x1 += ks2 + 1u;
  TFR(17) TFR(29) TFR(16) TFR(24)  x0 += ks2; x1 += k0 + 2u;
  TFR(13) TFR(15) TFR(26) TFR(6)   x0 += k0;  x1 += k1 + 3u;
  TFR(17) TFR(29) TFR(16) TFR(24)  x0 += k1;  x1 += ks2 + 4u;
  TFR(13) TFR(15) TFR(26) TFR(6)   x0 += ks2; x1 += k0 + 5u;
#undef TFR
  o0 = x0; o1 = x1;
}

// wave64 butterfly sum
__device__ inline float wred(float v) {
#pragma unroll
  for (int i = 32; i > 0; i >>= 1) v += __shfl_xor(v, i, 64);
  return v;
}

__device__ inline float blk_sum(float v, float* sm) {
  int t = threadIdx.x;
  sm[t] = v; __syncthreads();
  for (int off = 128; off > 0; off >>= 1) {
    if (t < off) sm[t] += sm[t + off];
    __syncthreads();
  }
  float r = sm[0]; __syncthreads();
  return r;
}

__device__ inline float sl1(float x, float y, float w) {
  const float dd = fabsf(x - y) * w;
  return (dd < 1.f) ? 0.5f * dd * dd : dd - 0.5f;
}

__device__ inline float nll2(float s0, float s1, int lbl) {
  const float mx = fmaxf(s0, s1);
  const float mn = fminf(s0, s1);
  const float l = mx + logf(1.0f + expf(mn - mx));
  return l - (lbl ? s1 : s0);
}

__device__ inline fx4 ldnt4(const float* p) {
  return __builtin_nontemporal_load((const fx4*)p);
}
__device__ inline ix4 ldnt4i(const int* p) {
  return __builtin_nontemporal_load((const ix4*)p);
}

// ---- Fused kernel: pixel blocks (0..2047) + hyp blocks (2048..2191) ----
__global__ __launch_bounds__(256, 4) void fused_kernel(
    const float* __restrict__ vpL, const float* __restrict__ vgL,
    const int*   __restrict__ mkL, const float* __restrict__ sgL,
    const float* __restrict__ vpR, const float* __restrict__ vgR,
    const int*   __restrict__ mkR, const float* __restrict__ sgR,
    const float* __restrict__ scL, const float* __restrict__ kpL,
    const float* __restrict__ k2L, const float* __restrict__ ofL,
    const float* __restrict__ scR, const float* __restrict__ kpR,
    const float* __restrict__ k2R, const float* __restrict__ ofR,
    const float* __restrict__ aPtr,
    uint32_t kLa, uint32_t kLb, uint32_t kRa, uint32_t kRb,
    float* __restrict__ ws) {
  const int t   = threadIdx.x;
  const int bid = blockIdx.x;

  if (bid < NPIXB) {
    // ================= pixel path =================
    const int side  = bid >> 10;
    const int v     = bid & 1023;
    const int b     = v >> 7;
    const int half  = (v >> 6) & 1;
    const int blk64 = v & 63;
    const int hwq   = blk64 * 256 + t;     // quad index 0..16383

    const float* vp = side ? vpR : vpL;
    const float* vg = side ? vgR : vgL;
    const int*   mk = side ? mkR : mkL;
    const float* sg = side ? sgR : sgL;

    // mask once (builtin NT load; compiler schedules/waits this one itself)
    const ix4 m4 = ldnt4i(mk + ((size_t)b << 16) + ((size_t)hwq << 2));
    const float w0 = (float)m4.x, w1 = (float)m4.y, w2 = (float)m4.z, w3 = (float)m4.w;

    // seg loads (half==0 blocks only; block-uniform branch)
    fx4 s0 = (fx4)0.f, s1 = (fx4)0.f;
    if (half == 0) {
      const size_t soff = ((size_t)b << 17) + ((size_t)hwq << 2);
      s0 = ldnt4(sg + soff);
      s1 = ldnt4(sg + soff + HWPIX);
    }

    // vertex channel walk: c = half*9 + j, j = 0..8
    const size_t pbase = ((size_t)(b * NCH + half * 9) << 16) + ((size_t)hwq << 2);
    const float* pp = vp + pbase;
    const float* qq = vg + pbase;

    // 18 inline-asm NT loads issued back-to-back -> 18 outstanding per wave
    fx4 P[9], Q[9];
#pragma unroll
    for (int j = 0; j < 9; ++j) {
      GL4NT(P[j], pp + (size_t)j * HWPIX);
      GL4NT(Q[j], qq + (size_t)j * HWPIX);
    }
    asm volatile("s_waitcnt vmcnt(0)" ::: "memory");
    __builtin_amdgcn_sched_barrier(0);   // keep compute below the wait (rule #18)

    float acc = 0.f;
#pragma unroll
    for (int j = 0; j < 9; ++j) {
      acc += sl1(P[j].x, Q[j].x, w0);
      acc += sl1(P[j].y, Q[j].y, w1);
      acc += sl1(P[j].z, Q[j].z, w2);
      acc += sl1(P[j].w, Q[j].w, w3);
    }

    // wave64 shuffle reduction + one cross-wave combine (1 barrier)
    __shared__ float smx[12];
    const int wid = t >> 6, lane = t & 63;
    const float vw = wred(acc);
    float cw = 0.f, gw = 0.f;
    if (half == 0) {
      const float cnt = w0 + w1 + w2 + w3;
      float seg = 0.f;
      seg += nll2(s0.x, s1.x, m4.x);
      seg += nll2(s0.y, s1.y, m4.y);
      seg += nll2(s0.z, s1.z, m4.z);
      seg += nll2(s0.w, s1.w, m4.w);
      cw = wred(cnt);
      gw = wred(seg);
    }
    if (lane == 0) {
      smx[wid] = vw;
      if (half == 0) { smx[4 + wid] = cw; smx[8 + wid] = gw; }
    }
    __syncthreads();
    if (t == 0) {
      ws[OFS_VOTE + side * NVB_SIDE + v] = smx[0] + smx[1] + smx[2] + smx[3];
      if (half == 0) {
        const int s = b * 64 + blk64;
        ws[OFS_CNT + side * NSB_SIDE + s] = smx[4] + smx[5] + smx[6] + smx[7];
        ws[OFS_SEG + side * NSB_SIDE + s] = smx[8] + smx[9] + smx[10] + smx[11];
      }
    }
    return;
  }

  // ================= hyp path =================
  const int hid  = bid - NPIXB;       // 0..143
  const int side = hid / NBK;
  const int bk   = hid % NBK;         // 0..71
  const float* sc = side ? scR : scL;
  const float* kp = side ? kpR : kpL;
  const float* k2 = side ? k2R : k2L;
  const float* of = side ? ofR : ofL;
  const uint32_t K0 = side ? kRa : kLa;
  const uint32_t K1 = side ? kRb : kLb;
  const int b = bk / NK, k = bk % NK;
  const float a = aPtr[0];
  const float kx = k2[(b * NK + k) * 2 + 0];
  const float ky = k2[(b * NK + k) * 2 + 1];
  const float2* kp2 = (const float2*)kp;

  float s[4], d[4], gv[4];
#pragma unroll
  for (int j = 0; j < 4; ++j) {
    const int n = t + j * 256;
    const size_t idx = ((size_t)b * NHYP + n) * NK + k;   // flat index of (b,n,k)
    s[j] = a * sc[idx];
    const float2 xy = kp2[idx];
    const float dx = xy.x - kx, dy = xy.y - ky;
    d[j] = sqrtf(dx * dx + dy * dy);
    // JAX partitionable random bits: bits = out0 ^ out1 of threefry(key, (0, flat_idx))
    uint32_t o0, o1;
    tf2x32(K0, K1, 0u, (uint32_t)idx, o0, o1);
    const uint32_t bits = o0 ^ o1;
    float u = __uint_as_float((bits >> 9) | 0x3F800000u) - 1.0f;   // [0,1)
    u = fmaxf(TINYF, u * (1.0f - TINYF) + TINYF);                  // uniform(tiny, 1)
    gv[j] = -logf(-logf(u)) + s[j];                                // gumbel + logits
  }

  __shared__ float sm[256];
  __shared__ int   si[256];

  // block max of logits
  float mx = fmaxf(fmaxf(s[0], s[1]), fmaxf(s[2], s[3]));
  sm[t] = mx; __syncthreads();
  for (int off = 128; off > 0; off >>= 1) {
    if (t < off) sm[t] = fmaxf(sm[t], sm[t + off]);
    __syncthreads();
  }
  mx = sm[0]; __syncthreads();

  float Z = 0.f, Sd = 0.f, Ss = 0.f;
#pragma unroll
  for (int j = 0; j < 4; ++j) {
    const float e = expf(s[j] - mx);
    Z  += e;
    Sd += e * d[j];
    Ss += e * (s[j] - mx);
  }
  Z  = blk_sum(Z, sm);
  Sd = blk_sum(Sd, sm);
  Ss = blk_sum(Ss, sm);

  // argmax of gumbel+logits, first-index tie-break (matches jnp.argmax)
  float bv = gv[0]; int bi = t;
#pragma unroll
  for (int j = 1; j < 4; ++j) {
    const int n = t + j * 256;
    if (gv[j] > bv) { bv = gv[j]; bi = n; }
  }
  sm[t] = bv; si[t] = bi; __syncthreads();
  for (int off = 128; off > 0; off >>= 1) {
    if (t < off) {
      const float v2 = sm[t + off]; const int i2 = si[t + off];
      if (v2 > sm[t] || (v2 == sm[t] && i2 < si[t])) { sm[t] = v2; si[t] = i2; }
    }
    __syncthreads();
  }

  if (t == 0) {
    ws[OFS_KP  + side * NBK + bk] = Sd / Z;
    ws[OFS_ENT + side * NBK + bk] = (logf(Z) - Ss / Z) * INV_LOG2;  // entropy in bits
    const int n = si[0];
    ws[OFS_Y + side * NBK + bk] =
        kp2[((size_t)b * NHYP + n) * NK + k].y + of[b * 2 + 1];
  }
}

// ---- Kernel 2: stage-2 reductions + scalar combine ----
__global__ __launch_bounds__(256) void final_kernel(
    const int* __restrict__ epochPtr, const float* __restrict__ ws,
    float* __restrict__ out) {
  __shared__ float sm[256];
  const int t = threadIdx.x;
  float voteS[2], cntS[2], segS[2], kpS[2], entS[2];
  for (int side = 0; side < 2; ++side) {
    float a;
    a = 0.f; for (int j = t; j < NVB_SIDE; j += 256) a += ws[OFS_VOTE + side * NVB_SIDE + j];
    voteS[side] = blk_sum(a, sm);
    a = 0.f; for (int j = t; j < NSB_SIDE; j += 256) a += ws[OFS_CNT + side * NSB_SIDE + j];
    cntS[side] = blk_sum(a, sm);
    a = 0.f; for (int j = t; j < NSB_SIDE; j += 256) a += ws[OFS_SEG + side * NSB_SIDE + j];
    segS[side] = blk_sum(a, sm);
    a = (t < NBK) ? ws[OFS_KP + side * NBK + t] : 0.f;
    kpS[side] = blk_sum(a, sm);
    a = 0.f;
    if (t < 8) {
      float es = 0.f;
      for (int k = 0; k < NK; ++k) es += ws[OFS_ENT + side * NBK + t * NK + k];
      a = fabsf(es / (float)NK - 6.0f);
    }
    entS[side] = blk_sum(a, sm);
  }
  float e = 0.f;
  if (t < NBK) {
    const float dy = fabsf(ws[OFS_Y + t] - ws[OFS_Y + NBK + t]);
    e = isfinite(dy) ? dy : 0.f;
  }
  const float epiSum = blk_sum(e, sm);

  if (t == 0) {
    const float voteL = (cntS[0] > 0.f) ? voteS[0] / fmaxf(cntS[0], 1.f) / (float)NCH : voteS[0];
    const float voteR = (cntS[1] > 0.f) ? voteS[1] / fmaxf(cntS[1], 1.f) / (float)NCH : voteS[1];
    const float segL = segS[0] / 524288.f;
    const float segR = segS[1] / 524288.f;
    const float kpLm = kpS[0] / (float)NBK, kpRm = kpS[1] / (float)NBK;
    const float entL = entS[0] / 8.f, entR = entS[1] / 8.f;

    const float vote_loss = 0.5f * (voteL + voteR);
    const float seg_loss  = 0.5f * (segL + segR);
    const float kp_loss   = 0.5f * (kpLm + kpRm);
    const float ent_loss  = 0.5f * (entL + entR);
    const float kp_w  = 1.f / (1.f + expf(-0.5f * (20.f - kp_loss)));
    const float vote_w = 1.f - kp_w;
    float vertex;
    if (epochPtr[0] > 49) {
      const float epi = epiSum / (float)NBK;
      vertex = kp_w * (kp_loss + epi) + vote_w * vote_loss;
    } else {
      vertex = kp_w * kp_loss + vote_w * vote_loss;
    }
    out[0] = vertex + ent_loss + seg_loss;
  }
}

extern "C" void kernel_launch(void* const* d_in, const int* in_sizes, int n_in,
                              void* d_out, int out_size, void* d_ws, size_t ws_size,
                              hipStream_t stream) {
  (void)in_sizes; (void)n_in; (void)out_size; (void)ws_size;
  const float* vpL = (const float*)d_in[0];
  const float* vgL = (const float*)d_in[1];
  const int*   mkL = (const int*)  d_in[2];
  const float* sgL = (const float*)d_in[3];
  const float* kpL = (const float*)d_in[4];
  const float* scL = (const float*)d_in[5];
  const float* k2L = (const float*)d_in[6];
  const float* ofL = (const float*)d_in[7];
  const float* vpR = (const float*)d_in[8];
  const float* vgR = (const float*)d_in[9];
  const int*   mkR = (const int*)  d_in[10];
  const float* sgR = (const float*)d_in[11];
  const float* kpR = (const float*)d_in[12];
  const float* scR = (const float*)d_in[13];
  const float* k2R = (const float*)d_in[14];
  const float* ofR = (const float*)d_in[15];
  const float* aP  = (const float*)d_in[16];
  const int*   epP = (const int*)  d_in[17];
  float* ws  = (float*)d_ws;
  float* out = (float*)d_out;

  // jax.random.split(jax.random.key(1234)) — partitionable ("foldlike") split:
  // kL = threefry(key, (0,0)), kR = threefry(key, (0,1)), key = [0, 1234]
  uint32_t kLa, kLb, kRa, kRb;
  tf2x32(0u, 1234u, 0u, 0u, kLa, kLb);
  tf2x32(0u, 1234u, 0u, 1u, kRa, kRb);

  fused_kernel<<<NPIXB + 2 * NBK, 256, 0, stream>>>(
      vpL, vgL, mkL, sgL, vpR, vgR, mkR, sgR,
      scL, kpL, k2L, ofL, scR, kpR, k2R, ofR,
      aP, kLa, kLb, kRa, kRb, ws);
  final_kernel<<<1, 256, 0, stream>>>(epP, ws, out);
}